// Round 17
// baseline (425.525 us; speedup 1.0000x reference)
//
#include <hip/hip_runtime.h>
#include <math.h>

#define N_NODES 16384
#define DIM 128
#define HC 384          // HEADS * C
#define NEG_SLOPE 0.2f
#define KNN 16
#define KP2 10          // per-lane register pool size
#define NSEG 4
#define NCAND 160       // 4 lane-groups * NSEG * KP2
#define SEGC (N_NODES / NSEG)   // 4096
#define TILES32 (SEGC / 32)     // 128
#define LROW 272        // padded LDS row stride (bytes)
#define LBUF2 (32 * LROW)       // 8704 B per buffer (32 rows)

typedef _Float16 f16x8 __attribute__((ext_vector_type(8)));
typedef _Float16 f16x2 __attribute__((ext_vector_type(2)));
typedef float f32x4 __attribute__((ext_vector_type(4)));
typedef unsigned long long u64;

// ---------------- prep 1: sq + split x into f16 hi/lo ----------------
__global__ __launch_bounds__(256) void prep_x(const float* __restrict__ x,
                                              float* __restrict__ sq,
                                              _Float16* __restrict__ xhi,
                                              _Float16* __restrict__ xlo) {
  const int wv = threadIdx.x >> 6;
  const int lane = threadIdx.x & 63;
  const int row = blockIdx.x * 4 + wv;
  const float2 v = *(const float2*)&x[row * DIM + lane * 2];
  float s = v.x * v.x + v.y * v.y;
  #pragma unroll
  for (int off = 32; off > 0; off >>= 1) s += __shfl_down(s, off);
  _Float16 h0 = (_Float16)v.x, h1 = (_Float16)v.y;
  _Float16 l0 = (_Float16)(v.x - (float)h0), l1 = (_Float16)(v.y - (float)h1);
  f16x2 hh; hh[0] = h0; hh[1] = h1;
  f16x2 ll; ll[0] = l0; ll[1] = l1;
  *(f16x2*)&xhi[row * DIM + lane * 2] = hh;
  *(f16x2*)&xlo[row * DIM + lane * 2] = ll;
  if (lane == 0) sq[row] = s;
}

// ---------------- prep 2: W transpose + split (WT[c][k]) ----------------
__global__ __launch_bounds__(256) void prep_w(const float* __restrict__ Wl,
                                              const float* __restrict__ Wr,
                                              _Float16* __restrict__ wthi,
                                              _Float16* __restrict__ wtlo) {
  const int t = blockIdx.x * 256 + threadIdx.x;   // [0, 98304)
  const int mat = t / 49152;
  const int e = t - mat * 49152;                  // e = k*384 + c
  const int k = e / HC;
  const int c = e - k * HC;
  const float w = (mat ? Wr : Wl)[e];
  _Float16 h = (_Float16)w;
  _Float16 l = (_Float16)(w - (float)h);
  wthi[mat * 49152 + c * DIM + k] = h;
  wtlo[mat * 49152 + c * DIM + k] = l;
}

// ---------------- xl = x@Wl, xr = x@Wr via MFMA f16-split (16x64 per wave) ----------------
__global__ __launch_bounds__(256) void gemm_xw_mfma(const _Float16* __restrict__ xhi,
                                                    const _Float16* __restrict__ xlo,
                                                    const _Float16* __restrict__ wthi,
                                                    const _Float16* __restrict__ wtlo,
                                                    _Float16* __restrict__ xl,
                                                    _Float16* __restrict__ xr) {
  const int lane = threadIdx.x & 63;
  const int wid = blockIdx.x * 4 + (threadIdx.x >> 6);  // [0, 12288)
  const int mat = wid / 6144;
  const int rem = wid - mat * 6144;
  const int rt = rem / 6;          // row tile [0,1024)
  const int ctg = rem - rt * 6;    // col group [0,6): 4 col-tiles each
  const int r0 = lane & 15;
  const int g8 = (lane >> 4) * 8;

  const _Float16* ap_hi = xhi + (size_t)(rt * 16 + r0) * DIM + g8;
  const _Float16* ap_lo = xlo + (size_t)(rt * 16 + r0) * DIM + g8;
  f16x8 ah[4], al[4];
  #pragma unroll
  for (int ks = 0; ks < 4; ks++) {
    ah[ks] = *(const f16x8*)(ap_hi + ks * 32);
    al[ks] = *(const f16x8*)(ap_lo + ks * 32);
  }
  _Float16* o = mat ? xr : xl;

  #pragma unroll
  for (int ct4 = 0; ct4 < 4; ct4++) {
    const int ct = ctg * 4 + ct4;
    const _Float16* bp_hi = wthi + mat * 49152 + (ct * 16 + r0) * DIM + g8;
    const _Float16* bp_lo = wtlo + mat * 49152 + (ct * 16 + r0) * DIM + g8;
    f32x4 acc = {0.f, 0.f, 0.f, 0.f};
    #pragma unroll
    for (int ks = 0; ks < 4; ks++) {
      f16x8 bh = *(const f16x8*)(bp_hi + ks * 32);
      f16x8 bl = *(const f16x8*)(bp_lo + ks * 32);
      acc = __builtin_amdgcn_mfma_f32_16x16x32_f16(ah[ks], bh, acc, 0, 0, 0);
      acc = __builtin_amdgcn_mfma_f32_16x16x32_f16(ah[ks], bl, acc, 0, 0, 0);
      acc = __builtin_amdgcn_mfma_f32_16x16x32_f16(al[ks], bh, acc, 0, 0, 0);
    }
    #pragma unroll
    for (int i = 0; i < 4; i++) {
      const int row = rt * 16 + (lane >> 4) * 4 + i;
      o[(size_t)row * HC + ct * 16 + r0] = (_Float16)acc[i];
    }
  }
}

// ---------------- knn: LDS-shared 32-col tiles + packed-u32 top-10 ----------------
__device__ __forceinline__ unsigned umin32(unsigned a, unsigned b) { return a < b ? a : b; }
__device__ __forceinline__ unsigned umax32(unsigned a, unsigned b) { return a > b ? a : b; }

__device__ __forceinline__ void ripple(unsigned pk, unsigned* pool) {
  unsigned cur = pk;
  #pragma unroll
  for (int s = 0; s < KP2; s++) {
    const unsigned mn = umin32(cur, pool[s]);
    cur = umax32(cur, pool[s]);
    pool[s] = mn;
  }
}

__device__ __forceinline__ void insert4s(const f32x4 acc, const f32x4 scv,
                                         int cb_cg, int selfid, unsigned* pool) {
  unsigned k0, k1, k2, k3;
  {
    unsigned kk[4];
    #pragma unroll
    for (int r = 0; r < 4; r++) {
      const int cid = cb_cg + r;
      const float key = fmaf(-2.f, acc[r], scv[r]);  // d - sr (sr const per lane)
      unsigned u = __float_as_uint(key);
      u ^= (unsigned)(((int)u >> 31) | 0x80000000u); // monotone flip
      unsigned pk = (u & 0xFFFFC000u) | (unsigned)cid;
      kk[r] = (cid == selfid) ? 0xFFFFFFFFu : pk;
    }
    k0 = kk[0]; k1 = kk[1]; k2 = kk[2]; k3 = kk[3];
  }
  #define CSWAP(a, b) { const unsigned mn = umin32(a, b), mx = umax32(a, b); a = mn; b = mx; }
  CSWAP(k0, k1) CSWAP(k2, k3) CSWAP(k0, k2) CSWAP(k1, k3) CSWAP(k1, k2)
  #undef CSWAP
  ripple(k0, pool);
  if (k1 < pool[KP2 - 1]) {
    ripple(k1, pool);
    ripple(k2, pool);
    ripple(k3, pool);
  }
}

__global__ __launch_bounds__(256) void knn_kernel(const _Float16* __restrict__ xhi,
                                                  const float* __restrict__ sq,
                                                  int* __restrict__ cand) {
  __shared__ __align__(16) char lds[2 * LBUF2];   // 17408 B

  const int lane = threadIdx.x & 63;
  const int w = threadIdx.x >> 6;
  const int seg = __builtin_amdgcn_readfirstlane(blockIdx.x & 3);
  const int rowgroup = __builtin_amdgcn_readfirstlane((blockIdx.x >> 2) * 4 + w);
  const int rowbase = rowgroup * 16;
  const int segbase = seg * SEGC;
  const int r0 = lane & 15;
  const int g8 = (lane >> 4) * 8;
  const int cg4 = (lane >> 4) * 4;
  const int selfid = rowbase + r0;

  // staging: each thread stages 2 rows (st_row, st_row+16), one 16B chunk each
  const int st_row = 4 * w + (lane >> 4);          // 0..15
  const int st_chunk = lane & 15;
  const size_t st_src0 = (size_t)st_row * DIM + st_chunk * 8;
  const size_t st_src1 = (size_t)(st_row + 16) * DIM + st_chunk * 8;
  char* const st_dst0 = &lds[st_row * LROW + st_chunk * 16];
  char* const st_dst1 = &lds[(st_row + 16) * LROW + st_chunk * 16];

  // stationary B: this wave's 16 row-features
  f16x8 b[4];
  {
    const size_t rb = (size_t)(rowbase + r0) * DIM + g8;
    #pragma unroll
    for (int ks = 0; ks < 4; ks++) b[ks] = *(const f16x8*)&xhi[rb + ks * 32];
  }

  unsigned pool[KP2];
  #pragma unroll
  for (int j = 0; j < KP2; j++) pool[j] = 0xFFFFFFFFu;

  // prologue: stage tile 0 into buf 0
  {
    const float4 g0 = *(const float4*)&xhi[(size_t)segbase * DIM + st_src0];
    const float4 g1 = *(const float4*)&xhi[(size_t)segbase * DIM + st_src1];
    *(float4*)(st_dst0) = g0;
    *(float4*)(st_dst1) = g1;
  }
  f32x4 sA0 = *(const f32x4*)&sq[segbase + cg4];
  f32x4 sA1 = *(const f32x4*)&sq[segbase + 16 + cg4];
  __syncthreads();

  int cur = 0;
  for (int t = 0; t < TILES32; t++) {
    const int tn = (t + 1) & (TILES32 - 1);
    const size_t nb = (size_t)(segbase + tn * 32) * DIM;
    const float4 g0 = *(const float4*)&xhi[nb + st_src0];
    const float4 g1 = *(const float4*)&xhi[nb + st_src1];
    const f32x4 sN0 = *(const f32x4*)&sq[segbase + tn * 32 + cg4];
    const f32x4 sN1 = *(const f32x4*)&sq[segbase + tn * 32 + 16 + cg4];

    // fragments for both 16-col subtiles
    const char* rb0 = &lds[cur * LBUF2 + r0 * LROW + g8 * 2];
    const char* rb1 = &lds[cur * LBUF2 + (16 + r0) * LROW + g8 * 2];
    f16x8 a0[4], a1[4];
    #pragma unroll
    for (int ks = 0; ks < 4; ks++) {
      a0[ks] = *(const f16x8*)(rb0 + ks * 64);
      a1[ks] = *(const f16x8*)(rb1 + ks * 64);
    }

    f32x4 acc0 = {0.f, 0.f, 0.f, 0.f};
    f32x4 acc1 = {0.f, 0.f, 0.f, 0.f};
    #pragma unroll
    for (int ks = 0; ks < 4; ks++) {
      acc0 = __builtin_amdgcn_mfma_f32_16x16x32_f16(a0[ks], b[ks], acc0, 0, 0, 0);
      acc1 = __builtin_amdgcn_mfma_f32_16x16x32_f16(a1[ks], b[ks], acc1, 0, 0, 0);
    }

    insert4s(acc0, sA0, segbase + t * 32 + cg4, selfid, pool);
    insert4s(acc1, sA1, segbase + t * 32 + 16 + cg4, selfid, pool);

    // write staged tile t+1 into the other buffer, then single barrier
    *(float4*)(st_dst0 + (cur ^ 1) * LBUF2) = g0;
    *(float4*)(st_dst1 + (cur ^ 1) * LBUF2) = g1;
    __syncthreads();
    sA0 = sN0; sA1 = sN1;
    cur ^= 1;
  }

  // dump: row = rowbase + r0; slot block = (lanegroup, seg)
  const int row = rowbase + r0;
  int* dst = cand + (size_t)row * NCAND + ((lane >> 4) * NSEG + seg) * KP2;
  #pragma unroll
  for (int e = 0; e < KP2; e++) dst[e] = (int)(pool[e] & 0x3FFFu);
}

// ---------------- refine v4: coalesced gather (8 lanes per candidate row) ----------------
__device__ __forceinline__ unsigned flip32(float f) {
  unsigned u = __float_as_uint(f);
  return u ^ (unsigned)(((int)u >> 31) | 0x80000000u);
}
__device__ __forceinline__ u64 umin64(u64 a, u64 b) { return a < b ? a : b; }

__global__ __launch_bounds__(256) void refine_kernel(const float* __restrict__ x,
                                                     const float* __restrict__ sq,
                                                     const int* __restrict__ cand,
                                                     int* __restrict__ idxo) {
  __shared__ __align__(16) float Xrow[4][DIM];     // 2 KB
  __shared__ u64 Keys[4][NCAND];                   // 5 KB
  const int wv = threadIdx.x >> 6;
  const int lane = threadIdx.x & 63;
  const int row = blockIdx.x * 4 + wv;

  {
    const float2 v = *(const float2*)&x[(size_t)row * DIM + lane * 2];
    *(float2*)&Xrow[wv][lane * 2] = v;
  }

  const int cs = lane >> 3;    // candidate slot within iteration (0..7)
  const int ch8 = lane & 7;    // 16B chunk id (0..7)
  const int base = row * NCAND;
  const float sr = sq[row];

  #pragma nounroll
  for (int it = 0; it < 20; it++) {
    const int ci = it * 8 + cs;
    const int c = cand[base + ci];
    const float4* p = (const float4*)&x[(size_t)c * DIM];
    float d = 0.f;
    #pragma unroll
    for (int j = 0; j < 4; j++) {
      const float4 a = p[ch8 + 8 * j];
      const float4 xv = *(const float4*)&Xrow[wv][(ch8 + 8 * j) * 4];
      d += xv.x * a.x + xv.y * a.y + xv.z * a.z + xv.w * a.w;
    }
    d += __shfl_xor(d, 1);
    d += __shfl_xor(d, 2);
    d += __shfl_xor(d, 4);
    if (ch8 == 0) {
      const float dist = sr + sq[c] - 2.f * d;
      Keys[wv][ci] = ((u64)flip32(dist) << 32) | (unsigned)c;
    }
  }

  u64 k0 = Keys[wv][lane];
  u64 k1 = Keys[wv][64 + lane];
  u64 k2 = (lane < 32) ? Keys[wv][128 + lane] : ~0ull;

  int* dst = idxo + (size_t)row * KNN;
  #pragma unroll
  for (int e = 0; e < KNN; e++) {
    u64 m = umin64(k0, umin64(k1, k2));
    #pragma unroll
    for (int off = 32; off > 0; off >>= 1) {
      const u64 o = __shfl_xor(m, off);
      m = umin64(m, o);
    }
    if (k0 == m)      { dst[e] = (int)(unsigned)m; k0 = ~0ull; }
    else if (k1 == m) { dst[e] = (int)(unsigned)m; k1 = ~0ull; }
    else if (k2 == m) { dst[e] = (int)(unsigned)m; k2 = ~0ull; }
  }
}

// ---------------- attention epilogue (4 nodes / 256-thr block, f16x2 channels) ----------------
__global__ __launch_bounds__(256) void attn_kernel(const _Float16* __restrict__ xl,
                                                   const _Float16* __restrict__ xr,
                                                   const float* __restrict__ att,
                                                   const float* __restrict__ bias,
                                                   const int* __restrict__ idxo,
                                                   float* __restrict__ out) {
  const int n = blockIdx.x * 4 + (threadIdx.x >> 6);
  const int lane = threadIdx.x & 63;
  const int ch = lane * 2;
  int myn = 0;
  if (lane < KNN) myn = idxo[(size_t)n * KNN + lane];
  float o0 = 0.f, o1 = 0.f;
  #pragma unroll
  for (int h = 0; h < 3; h++) {
    const f16x2 rr = *(const f16x2*)&xr[(size_t)n * HC + h * 128 + ch];
    const float r0 = (float)rr[0], r1 = (float)rr[1];
    const float2 av = *(const float2*)&att[h * 128 + ch];
    float v0[KNN], v1[KNN], e[KNN];
    #pragma unroll
    for (int kk = 0; kk < KNN; kk++) {
      const f16x2 xv = *(const f16x2*)&xl[(size_t)__shfl(myn, kk) * HC + h * 128 + ch];
      const float x0 = (float)xv[0], x1 = (float)xv[1];
      v0[kk] = x0; v1[kk] = x1;
      float g0 = x0 + r0; g0 = g0 >= 0.f ? g0 : NEG_SLOPE * g0;
      float g1 = x1 + r1; g1 = g1 >= 0.f ? g1 : NEG_SLOPE * g1;
      float p = av.x * g0 + av.y * g1;
      #pragma unroll
      for (int off = 32; off > 0; off >>= 1) p += __shfl_xor(p, off);
      e[kk] = p;
    }
    float m = e[0];
    #pragma unroll
    for (int kk = 1; kk < KNN; kk++) m = fmaxf(m, e[kk]);
    float s = 0.f;
    float w[KNN];
    #pragma unroll
    for (int kk = 0; kk < KNN; kk++) { w[kk] = expf(e[kk] - m); s += w[kk]; }
    #pragma unroll
    for (int kk = 0; kk < KNN; kk++) {
      const float al = w[kk] / s;
      o0 += al * v0[kk];
      o1 += al * v1[kk];
    }
  }
  const float2 bv = *(const float2*)&bias[ch];
  float2 ov;
  ov.x = o0 / 3.f + bv.x;
  ov.y = o1 / 3.f + bv.y;
  *(float2*)&out[(size_t)n * 128 + ch] = ov;
}

extern "C" void kernel_launch(void* const* d_in, const int* in_sizes, int n_in,
                              void* d_out, int out_size, void* d_ws, size_t ws_size,
                              hipStream_t stream) {
  const float* x    = (const float*)d_in[0];
  const float* Wl   = (const float*)d_in[1];
  const float* Wr   = (const float*)d_in[2];
  const float* att  = (const float*)d_in[3];
  const float* bias = (const float*)d_in[4];
  float* out = (float*)d_out;

  _Float16* xhi  = (_Float16*)d_ws;                    // N*128
  _Float16* xlo  = xhi + (size_t)N_NODES * DIM;        // N*128
  _Float16* wthi = xlo + (size_t)N_NODES * DIM;        // 2*384*128
  _Float16* wtlo = wthi + 2 * HC * DIM;
  _Float16* xl   = wtlo + 2 * HC * DIM;                // N*384
  _Float16* xr   = xl + (size_t)N_NODES * HC;          // N*384
  float*    sqv  = (float*)(xr + (size_t)N_NODES * HC);
  int*      cnd  = (int*)(sqv + N_NODES);              // N*160
  int*      idx  = cnd + (size_t)N_NODES * NCAND;      // N*16

  prep_x<<<N_NODES / 4, 256, 0, stream>>>(x, sqv, xhi, xlo);
  prep_w<<<384, 256, 0, stream>>>(Wl, Wr, wthi, wtlo);
  gemm_xw_mfma<<<3072, 256, 0, stream>>>(xhi, xlo, wthi, wtlo, xl, xr);
  knn_kernel<<<N_NODES / 16, 256, 0, stream>>>(xhi, sqv, cnd);
  refine_kernel<<<N_NODES / 4, 256, 0, stream>>>(x, sqv, cnd, idx);
  attn_kernel<<<N_NODES / 4, 256, 0, stream>>>(xl, xr, att, bias, idx, out);
}

// Round 18
// 421.324 us; speedup vs baseline: 1.0100x; 1.0100x over previous
//
#include <hip/hip_runtime.h>
#include <math.h>

#define N_NODES 16384
#define DIM 128
#define HC 384          // HEADS * C
#define NEG_SLOPE 0.2f
#define KNN 16
#define KP2 10          // per-lane register pool size
#define NSEG 4
#define NCAND 160       // 4 lane-groups * NSEG * KP2
#define SEGC (N_NODES / NSEG)   // 4096
#define TILES64 (SEGC / 64)     // 64
#define LROW 272        // padded LDS row stride (bytes)
#define LBUF64 (64 * LROW)      // 17408 B per buffer (64 rows)

typedef _Float16 f16x8 __attribute__((ext_vector_type(8)));
typedef _Float16 f16x2 __attribute__((ext_vector_type(2)));
typedef float f32x4 __attribute__((ext_vector_type(4)));
typedef unsigned long long u64;

// ---------------- prep 1: sq + split x into f16 hi/lo ----------------
__global__ __launch_bounds__(256) void prep_x(const float* __restrict__ x,
                                              float* __restrict__ sq,
                                              _Float16* __restrict__ xhi,
                                              _Float16* __restrict__ xlo) {
  const int wv = threadIdx.x >> 6;
  const int lane = threadIdx.x & 63;
  const int row = blockIdx.x * 4 + wv;
  const float2 v = *(const float2*)&x[row * DIM + lane * 2];
  float s = v.x * v.x + v.y * v.y;
  #pragma unroll
  for (int off = 32; off > 0; off >>= 1) s += __shfl_down(s, off);
  _Float16 h0 = (_Float16)v.x, h1 = (_Float16)v.y;
  _Float16 l0 = (_Float16)(v.x - (float)h0), l1 = (_Float16)(v.y - (float)h1);
  f16x2 hh; hh[0] = h0; hh[1] = h1;
  f16x2 ll; ll[0] = l0; ll[1] = l1;
  *(f16x2*)&xhi[row * DIM + lane * 2] = hh;
  *(f16x2*)&xlo[row * DIM + lane * 2] = ll;
  if (lane == 0) sq[row] = s;
}

// ---------------- prep 2: W transpose + split (WT[c][k]) ----------------
__global__ __launch_bounds__(256) void prep_w(const float* __restrict__ Wl,
                                              const float* __restrict__ Wr,
                                              _Float16* __restrict__ wthi,
                                              _Float16* __restrict__ wtlo) {
  const int t = blockIdx.x * 256 + threadIdx.x;   // [0, 98304)
  const int mat = t / 49152;
  const int e = t - mat * 49152;                  // e = k*384 + c
  const int k = e / HC;
  const int c = e - k * HC;
  const float w = (mat ? Wr : Wl)[e];
  _Float16 h = (_Float16)w;
  _Float16 l = (_Float16)(w - (float)h);
  wthi[mat * 49152 + c * DIM + k] = h;
  wtlo[mat * 49152 + c * DIM + k] = l;
}

// ---------------- xl = x@Wl, xr = x@Wr via MFMA f16-split (16x64 per wave) ----------------
__global__ __launch_bounds__(256) void gemm_xw_mfma(const _Float16* __restrict__ xhi,
                                                    const _Float16* __restrict__ xlo,
                                                    const _Float16* __restrict__ wthi,
                                                    const _Float16* __restrict__ wtlo,
                                                    _Float16* __restrict__ xl,
                                                    _Float16* __restrict__ xr) {
  const int lane = threadIdx.x & 63;
  const int wid = blockIdx.x * 4 + (threadIdx.x >> 6);  // [0, 12288)
  const int mat = wid / 6144;
  const int rem = wid - mat * 6144;
  const int rt = rem / 6;          // row tile [0,1024)
  const int ctg = rem - rt * 6;    // col group [0,6): 4 col-tiles each
  const int r0 = lane & 15;
  const int g8 = (lane >> 4) * 8;

  const _Float16* ap_hi = xhi + (size_t)(rt * 16 + r0) * DIM + g8;
  const _Float16* ap_lo = xlo + (size_t)(rt * 16 + r0) * DIM + g8;
  f16x8 ah[4], al[4];
  #pragma unroll
  for (int ks = 0; ks < 4; ks++) {
    ah[ks] = *(const f16x8*)(ap_hi + ks * 32);
    al[ks] = *(const f16x8*)(ap_lo + ks * 32);
  }
  _Float16* o = mat ? xr : xl;

  #pragma unroll
  for (int ct4 = 0; ct4 < 4; ct4++) {
    const int ct = ctg * 4 + ct4;
    const _Float16* bp_hi = wthi + mat * 49152 + (ct * 16 + r0) * DIM + g8;
    const _Float16* bp_lo = wtlo + mat * 49152 + (ct * 16 + r0) * DIM + g8;
    f32x4 acc = {0.f, 0.f, 0.f, 0.f};
    #pragma unroll
    for (int ks = 0; ks < 4; ks++) {
      f16x8 bh = *(const f16x8*)(bp_hi + ks * 32);
      f16x8 bl = *(const f16x8*)(bp_lo + ks * 32);
      acc = __builtin_amdgcn_mfma_f32_16x16x32_f16(ah[ks], bh, acc, 0, 0, 0);
      acc = __builtin_amdgcn_mfma_f32_16x16x32_f16(ah[ks], bl, acc, 0, 0, 0);
      acc = __builtin_amdgcn_mfma_f32_16x16x32_f16(al[ks], bh, acc, 0, 0, 0);
    }
    #pragma unroll
    for (int i = 0; i < 4; i++) {
      const int row = rt * 16 + (lane >> 4) * 4 + i;
      o[(size_t)row * HC + ct * 16 + r0] = (_Float16)acc[i];
    }
  }
}

// ---------------- knn: LDS-shared 64-col tiles + packed-u32 top-10 ----------------
__device__ __forceinline__ unsigned umin32(unsigned a, unsigned b) { return a < b ? a : b; }
__device__ __forceinline__ unsigned umax32(unsigned a, unsigned b) { return a > b ? a : b; }

__device__ __forceinline__ void ripple(unsigned pk, unsigned* pool) {
  unsigned cur = pk;
  #pragma unroll
  for (int s = 0; s < KP2; s++) {
    const unsigned mn = umin32(cur, pool[s]);
    cur = umax32(cur, pool[s]);
    pool[s] = mn;
  }
}

__device__ __forceinline__ void insert4s(const f32x4 acc, const f32x4 scv,
                                         int cb_cg, int selfid, unsigned* pool) {
  unsigned k0, k1, k2, k3;
  {
    unsigned kk[4];
    #pragma unroll
    for (int r = 0; r < 4; r++) {
      const int cid = cb_cg + r;
      const float key = fmaf(-2.f, acc[r], scv[r]);  // d - sr (sr const per lane)
      unsigned u = __float_as_uint(key);
      u ^= (unsigned)(((int)u >> 31) | 0x80000000u); // monotone flip
      unsigned pk = (u & 0xFFFFC000u) | (unsigned)cid;
      kk[r] = (cid == selfid) ? 0xFFFFFFFFu : pk;
    }
    k0 = kk[0]; k1 = kk[1]; k2 = kk[2]; k3 = kk[3];
  }
  #define CSWAP(a, b) { const unsigned mn = umin32(a, b), mx = umax32(a, b); a = mn; b = mx; }
  CSWAP(k0, k1) CSWAP(k2, k3) CSWAP(k0, k2) CSWAP(k1, k3) CSWAP(k1, k2)
  #undef CSWAP
  ripple(k0, pool);
  if (k1 < pool[KP2 - 1]) {
    ripple(k1, pool);
    ripple(k2, pool);
    ripple(k3, pool);
  }
}

__global__ __launch_bounds__(256) void knn_kernel(const _Float16* __restrict__ xhi,
                                                  const float* __restrict__ sq,
                                                  int* __restrict__ cand) {
  __shared__ __align__(16) char lds[2 * LBUF64];   // 34816 B

  const int lane = threadIdx.x & 63;
  const int w = threadIdx.x >> 6;
  const int seg = __builtin_amdgcn_readfirstlane(blockIdx.x & 3);
  const int rowgroup = __builtin_amdgcn_readfirstlane((blockIdx.x >> 2) * 4 + w);
  const int rowbase = rowgroup * 16;
  const int segbase = seg * SEGC;
  const int r0 = lane & 15;
  const int g8 = (lane >> 4) * 8;
  const int cg4 = (lane >> 4) * 4;
  const int selfid = rowbase + r0;

  // staging: each thread stages 4 rows (st_row + 16k), one 16B chunk each
  const int st_row = 4 * w + (lane >> 4);          // 0..15
  const int st_chunk = lane & 15;
  size_t st_src[4];
  char* st_dst[4];
  #pragma unroll
  for (int k = 0; k < 4; k++) {
    st_src[k] = (size_t)(st_row + 16 * k) * DIM + st_chunk * 8;
    st_dst[k] = &lds[(st_row + 16 * k) * LROW + st_chunk * 16];
  }

  // stationary B: this wave's 16 row-features
  f16x8 b[4];
  {
    const size_t rb = (size_t)(rowbase + r0) * DIM + g8;
    #pragma unroll
    for (int ks = 0; ks < 4; ks++) b[ks] = *(const f16x8*)&xhi[rb + ks * 32];
  }

  unsigned pool[KP2];
  #pragma unroll
  for (int j = 0; j < KP2; j++) pool[j] = 0xFFFFFFFFu;

  // prologue: stage tile 0 into buf 0; preload sq(tile 0)
  {
    const size_t tb = (size_t)segbase * DIM;
    #pragma unroll
    for (int k = 0; k < 4; k++)
      *(float4*)(st_dst[k]) = *(const float4*)&xhi[tb + st_src[k]];
  }
  f32x4 sA[4];
  #pragma unroll
  for (int s = 0; s < 4; s++) sA[s] = *(const f32x4*)&sq[segbase + 16 * s + cg4];
  __syncthreads();

  int cur = 0;
  for (int t = 0; t < TILES64; t++) {
    const int tn = (t + 1) & (TILES64 - 1);
    const size_t nb = (size_t)(segbase + tn * 64) * DIM;
    float4 g[4];
    #pragma unroll
    for (int k = 0; k < 4; k++) g[k] = *(const float4*)&xhi[nb + st_src[k]];
    f32x4 sN[4];
    #pragma unroll
    for (int s = 0; s < 4; s++) sN[s] = *(const f32x4*)&sq[segbase + tn * 64 + 16 * s + cg4];

    const int cb = segbase + t * 64;
    // process 4 subtiles in 2 register-reuse pairs
    #pragma unroll
    for (int pr = 0; pr < 2; pr++) {
      const int s0 = pr * 2, s1 = pr * 2 + 1;
      const char* rb0 = &lds[cur * LBUF64 + (16 * s0 + r0) * LROW + g8 * 2];
      const char* rb1 = &lds[cur * LBUF64 + (16 * s1 + r0) * LROW + g8 * 2];
      f16x8 a0[4], a1[4];
      #pragma unroll
      for (int ks = 0; ks < 4; ks++) {
        a0[ks] = *(const f16x8*)(rb0 + ks * 64);
        a1[ks] = *(const f16x8*)(rb1 + ks * 64);
      }
      f32x4 acc0 = {0.f, 0.f, 0.f, 0.f};
      f32x4 acc1 = {0.f, 0.f, 0.f, 0.f};
      #pragma unroll
      for (int ks = 0; ks < 4; ks++) {
        acc0 = __builtin_amdgcn_mfma_f32_16x16x32_f16(a0[ks], b[ks], acc0, 0, 0, 0);
        acc1 = __builtin_amdgcn_mfma_f32_16x16x32_f16(a1[ks], b[ks], acc1, 0, 0, 0);
      }
      insert4s(acc0, sA[s0], cb + 16 * s0 + cg4, selfid, pool);
      insert4s(acc1, sA[s1], cb + 16 * s1 + cg4, selfid, pool);
    }

    // write staged tile t+1 into the other buffer, then single barrier
    #pragma unroll
    for (int k = 0; k < 4; k++)
      *(float4*)(st_dst[k] + (cur ^ 1) * LBUF64) = g[k];
    __syncthreads();
    #pragma unroll
    for (int s = 0; s < 4; s++) sA[s] = sN[s];
    cur ^= 1;
  }

  // dump: row = rowbase + r0; slot block = (lanegroup, seg)
  const int row = rowbase + r0;
  int* dst = cand + (size_t)row * NCAND + ((lane >> 4) * NSEG + seg) * KP2;
  #pragma unroll
  for (int e = 0; e < KP2; e++) dst[e] = (int)(pool[e] & 0x3FFFu);
}

// ---------------- refine v4: coalesced gather (8 lanes per candidate row) ----------------
__device__ __forceinline__ unsigned flip32(float f) {
  unsigned u = __float_as_uint(f);
  return u ^ (unsigned)(((int)u >> 31) | 0x80000000u);
}
__device__ __forceinline__ u64 umin64(u64 a, u64 b) { return a < b ? a : b; }

__global__ __launch_bounds__(256) void refine_kernel(const float* __restrict__ x,
                                                     const float* __restrict__ sq,
                                                     const int* __restrict__ cand,
                                                     int* __restrict__ idxo) {
  __shared__ __align__(16) float Xrow[4][DIM];     // 2 KB
  __shared__ u64 Keys[4][NCAND];                   // 5 KB
  const int wv = threadIdx.x >> 6;
  const int lane = threadIdx.x & 63;
  const int row = blockIdx.x * 4 + wv;

  {
    const float2 v = *(const float2*)&x[(size_t)row * DIM + lane * 2];
    *(float2*)&Xrow[wv][lane * 2] = v;
  }

  const int cs = lane >> 3;    // candidate slot within iteration (0..7)
  const int ch8 = lane & 7;    // 16B chunk id (0..7)
  const int base = row * NCAND;
  const float sr = sq[row];

  #pragma nounroll
  for (int it = 0; it < 20; it++) {
    const int ci = it * 8 + cs;
    const int c = cand[base + ci];
    const float4* p = (const float4*)&x[(size_t)c * DIM];
    float d = 0.f;
    #pragma unroll
    for (int j = 0; j < 4; j++) {
      const float4 a = p[ch8 + 8 * j];
      const float4 xv = *(const float4*)&Xrow[wv][(ch8 + 8 * j) * 4];
      d += xv.x * a.x + xv.y * a.y + xv.z * a.z + xv.w * a.w;
    }
    d += __shfl_xor(d, 1);
    d += __shfl_xor(d, 2);
    d += __shfl_xor(d, 4);
    if (ch8 == 0) {
      const float dist = sr + sq[c] - 2.f * d;
      Keys[wv][ci] = ((u64)flip32(dist) << 32) | (unsigned)c;
    }
  }

  u64 k0 = Keys[wv][lane];
  u64 k1 = Keys[wv][64 + lane];
  u64 k2 = (lane < 32) ? Keys[wv][128 + lane] : ~0ull;

  int* dst = idxo + (size_t)row * KNN;
  #pragma unroll
  for (int e = 0; e < KNN; e++) {
    u64 m = umin64(k0, umin64(k1, k2));
    #pragma unroll
    for (int off = 32; off > 0; off >>= 1) {
      const u64 o = __shfl_xor(m, off);
      m = umin64(m, o);
    }
    if (k0 == m)      { dst[e] = (int)(unsigned)m; k0 = ~0ull; }
    else if (k1 == m) { dst[e] = (int)(unsigned)m; k1 = ~0ull; }
    else if (k2 == m) { dst[e] = (int)(unsigned)m; k2 = ~0ull; }
  }
}

// ---------------- attention epilogue (4 nodes / 256-thr block, f16x2 channels) ----------------
__global__ __launch_bounds__(256) void attn_kernel(const _Float16* __restrict__ xl,
                                                   const _Float16* __restrict__ xr,
                                                   const float* __restrict__ att,
                                                   const float* __restrict__ bias,
                                                   const int* __restrict__ idxo,
                                                   float* __restrict__ out) {
  const int n = blockIdx.x * 4 + (threadIdx.x >> 6);
  const int lane = threadIdx.x & 63;
  const int ch = lane * 2;
  int myn = 0;
  if (lane < KNN) myn = idxo[(size_t)n * KNN + lane];
  float o0 = 0.f, o1 = 0.f;
  #pragma unroll
  for (int h = 0; h < 3; h++) {
    const f16x2 rr = *(const f16x2*)&xr[(size_t)n * HC + h * 128 + ch];
    const float r0 = (float)rr[0], r1 = (float)rr[1];
    const float2 av = *(const float2*)&att[h * 128 + ch];
    float v0[KNN], v1[KNN], e[KNN];
    #pragma unroll
    for (int kk = 0; kk < KNN; kk++) {
      const f16x2 xv = *(const f16x2*)&xl[(size_t)__shfl(myn, kk) * HC + h * 128 + ch];
      const float x0 = (float)xv[0], x1 = (float)xv[1];
      v0[kk] = x0; v1[kk] = x1;
      float g0 = x0 + r0; g0 = g0 >= 0.f ? g0 : NEG_SLOPE * g0;
      float g1 = x1 + r1; g1 = g1 >= 0.f ? g1 : NEG_SLOPE * g1;
      float p = av.x * g0 + av.y * g1;
      #pragma unroll
      for (int off = 32; off > 0; off >>= 1) p += __shfl_xor(p, off);
      e[kk] = p;
    }
    float m = e[0];
    #pragma unroll
    for (int kk = 1; kk < KNN; kk++) m = fmaxf(m, e[kk]);
    float s = 0.f;
    float w[KNN];
    #pragma unroll
    for (int kk = 0; kk < KNN; kk++) { w[kk] = expf(e[kk] - m); s += w[kk]; }
    #pragma unroll
    for (int kk = 0; kk < KNN; kk++) {
      const float al = w[kk] / s;
      o0 += al * v0[kk];
      o1 += al * v1[kk];
    }
  }
  const float2 bv = *(const float2*)&bias[ch];
  float2 ov;
  ov.x = o0 / 3.f + bv.x;
  ov.y = o1 / 3.f + bv.y;
  *(float2*)&out[(size_t)n * 128 + ch] = ov;
}

extern "C" void kernel_launch(void* const* d_in, const int* in_sizes, int n_in,
                              void* d_out, int out_size, void* d_ws, size_t ws_size,
                              hipStream_t stream) {
  const float* x    = (const float*)d_in[0];
  const float* Wl   = (const float*)d_in[1];
  const float* Wr   = (const float*)d_in[2];
  const float* att  = (const float*)d_in[3];
  const float* bias = (const float*)d_in[4];
  float* out = (float*)d_out;

  _Float16* xhi  = (_Float16*)d_ws;                    // N*128
  _Float16* xlo  = xhi + (size_t)N_NODES * DIM;        // N*128
  _Float16* wthi = xlo + (size_t)N_NODES * DIM;        // 2*384*128
  _Float16* wtlo = wthi + 2 * HC * DIM;
  _Float16* xl   = wtlo + 2 * HC * DIM;                // N*384
  _Float16* xr   = xl + (size_t)N_NODES * HC;          // N*384
  float*    sqv  = (float*)(xr + (size_t)N_NODES * HC);
  int*      cnd  = (int*)(sqv + N_NODES);              // N*160
  int*      idx  = cnd + (size_t)N_NODES * NCAND;      // N*16

  prep_x<<<N_NODES / 4, 256, 0, stream>>>(x, sqv, xhi, xlo);
  prep_w<<<384, 256, 0, stream>>>(Wl, Wr, wthi, wtlo);
  gemm_xw_mfma<<<3072, 256, 0, stream>>>(xhi, xlo, wthi, wtlo, xl, xr);
  knn_kernel<<<N_NODES / 16, 256, 0, stream>>>(xhi, sqv, cnd);
  refine_kernel<<<N_NODES / 4, 256, 0, stream>>>(x, sqv, cnd, idx);
  attn_kernel<<<N_NODES / 4, 256, 0, stream>>>(xl, xr, att, bias, idx, out);
}

// Round 19
// 407.547 us; speedup vs baseline: 1.0441x; 1.0338x over previous
//
#include <hip/hip_runtime.h>
#include <math.h>

#define N_NODES 16384
#define DIM 128
#define HC 384          // HEADS * C
#define NEG_SLOPE 0.2f
#define KNN 16
#define KP2 6           // per-lane register pool size
#define NSEG 8
#define NCAND 192       // 4 lane-groups * NSEG * KP2 = 64*3
#define SEGC (N_NODES / NSEG)   // 2048
#define TILES32 (SEGC / 32)     // 64
#define LROW 272        // padded LDS row stride (bytes)
#define LBUF2 (32 * LROW)       // 8704 B per buffer (32 rows)

typedef _Float16 f16x8 __attribute__((ext_vector_type(8)));
typedef _Float16 f16x2 __attribute__((ext_vector_type(2)));
typedef float f32x4 __attribute__((ext_vector_type(4)));
typedef unsigned long long u64;

// ---------------- prep 1: sq + split x into f16 hi/lo ----------------
__global__ __launch_bounds__(256) void prep_x(const float* __restrict__ x,
                                              float* __restrict__ sq,
                                              _Float16* __restrict__ xhi,
                                              _Float16* __restrict__ xlo) {
  const int wv = threadIdx.x >> 6;
  const int lane = threadIdx.x & 63;
  const int row = blockIdx.x * 4 + wv;
  const float2 v = *(const float2*)&x[row * DIM + lane * 2];
  float s = v.x * v.x + v.y * v.y;
  #pragma unroll
  for (int off = 32; off > 0; off >>= 1) s += __shfl_down(s, off);
  _Float16 h0 = (_Float16)v.x, h1 = (_Float16)v.y;
  _Float16 l0 = (_Float16)(v.x - (float)h0), l1 = (_Float16)(v.y - (float)h1);
  f16x2 hh; hh[0] = h0; hh[1] = h1;
  f16x2 ll; ll[0] = l0; ll[1] = l1;
  *(f16x2*)&xhi[row * DIM + lane * 2] = hh;
  *(f16x2*)&xlo[row * DIM + lane * 2] = ll;
  if (lane == 0) sq[row] = s;
}

// ---------------- prep 2: W transpose + split (WT[c][k]) ----------------
__global__ __launch_bounds__(256) void prep_w(const float* __restrict__ Wl,
                                              const float* __restrict__ Wr,
                                              _Float16* __restrict__ wthi,
                                              _Float16* __restrict__ wtlo) {
  const int t = blockIdx.x * 256 + threadIdx.x;   // [0, 98304)
  const int mat = t / 49152;
  const int e = t - mat * 49152;                  // e = k*384 + c
  const int k = e / HC;
  const int c = e - k * HC;
  const float w = (mat ? Wr : Wl)[e];
  _Float16 h = (_Float16)w;
  _Float16 l = (_Float16)(w - (float)h);
  wthi[mat * 49152 + c * DIM + k] = h;
  wtlo[mat * 49152 + c * DIM + k] = l;
}

// ---------------- xl = x@Wl, xr = x@Wr via MFMA f16-split (16x64 per wave) ----------------
__global__ __launch_bounds__(256) void gemm_xw_mfma(const _Float16* __restrict__ xhi,
                                                    const _Float16* __restrict__ xlo,
                                                    const _Float16* __restrict__ wthi,
                                                    const _Float16* __restrict__ wtlo,
                                                    _Float16* __restrict__ xl,
                                                    _Float16* __restrict__ xr) {
  const int lane = threadIdx.x & 63;
  const int wid = blockIdx.x * 4 + (threadIdx.x >> 6);  // [0, 12288)
  const int mat = wid / 6144;
  const int rem = wid - mat * 6144;
  const int rt = rem / 6;          // row tile [0,1024)
  const int ctg = rem - rt * 6;    // col group [0,6): 4 col-tiles each
  const int r0 = lane & 15;
  const int g8 = (lane >> 4) * 8;

  const _Float16* ap_hi = xhi + (size_t)(rt * 16 + r0) * DIM + g8;
  const _Float16* ap_lo = xlo + (size_t)(rt * 16 + r0) * DIM + g8;
  f16x8 ah[4], al[4];
  #pragma unroll
  for (int ks = 0; ks < 4; ks++) {
    ah[ks] = *(const f16x8*)(ap_hi + ks * 32);
    al[ks] = *(const f16x8*)(ap_lo + ks * 32);
  }
  _Float16* o = mat ? xr : xl;

  #pragma unroll
  for (int ct4 = 0; ct4 < 4; ct4++) {
    const int ct = ctg * 4 + ct4;
    const _Float16* bp_hi = wthi + mat * 49152 + (ct * 16 + r0) * DIM + g8;
    const _Float16* bp_lo = wtlo + mat * 49152 + (ct * 16 + r0) * DIM + g8;
    f32x4 acc = {0.f, 0.f, 0.f, 0.f};
    #pragma unroll
    for (int ks = 0; ks < 4; ks++) {
      f16x8 bh = *(const f16x8*)(bp_hi + ks * 32);
      f16x8 bl = *(const f16x8*)(bp_lo + ks * 32);
      acc = __builtin_amdgcn_mfma_f32_16x16x32_f16(ah[ks], bh, acc, 0, 0, 0);
      acc = __builtin_amdgcn_mfma_f32_16x16x32_f16(ah[ks], bl, acc, 0, 0, 0);
      acc = __builtin_amdgcn_mfma_f32_16x16x32_f16(al[ks], bh, acc, 0, 0, 0);
    }
    #pragma unroll
    for (int i = 0; i < 4; i++) {
      const int row = rt * 16 + (lane >> 4) * 4 + i;
      o[(size_t)row * HC + ct * 16 + r0] = (_Float16)acc[i];
    }
  }
}

// ---------------- knn: LDS-shared 32-col tiles + packed-u32 top-6, 8 segs ----------------
__device__ __forceinline__ unsigned umin32(unsigned a, unsigned b) { return a < b ? a : b; }
__device__ __forceinline__ unsigned umax32(unsigned a, unsigned b) { return a > b ? a : b; }

__device__ __forceinline__ void ripple(unsigned pk, unsigned* pool) {
  unsigned cur = pk;
  #pragma unroll
  for (int s = 0; s < KP2; s++) {
    const unsigned mn = umin32(cur, pool[s]);
    cur = umax32(cur, pool[s]);
    pool[s] = mn;
  }
}

__device__ __forceinline__ void insert4s(const f32x4 acc, const f32x4 scv,
                                         int cb_cg, int selfid, unsigned* pool) {
  unsigned k0, k1, k2, k3;
  {
    unsigned kk[4];
    #pragma unroll
    for (int r = 0; r < 4; r++) {
      const int cid = cb_cg + r;
      const float key = fmaf(-2.f, acc[r], scv[r]);  // d - sr (sr const per lane)
      unsigned u = __float_as_uint(key);
      u ^= (unsigned)(((int)u >> 31) | 0x80000000u); // monotone flip
      unsigned pk = (u & 0xFFFFC000u) | (unsigned)cid;
      kk[r] = (cid == selfid) ? 0xFFFFFFFFu : pk;
    }
    k0 = kk[0]; k1 = kk[1]; k2 = kk[2]; k3 = kk[3];
  }
  #define CSWAP(a, b) { const unsigned mn = umin32(a, b), mx = umax32(a, b); a = mn; b = mx; }
  CSWAP(k0, k1) CSWAP(k2, k3) CSWAP(k0, k2) CSWAP(k1, k3) CSWAP(k1, k2)
  #undef CSWAP
  ripple(k0, pool);
  if (k1 < pool[KP2 - 1]) {
    ripple(k1, pool);
    ripple(k2, pool);
    ripple(k3, pool);
  }
}

__global__ __launch_bounds__(256, 8) void knn_kernel(const _Float16* __restrict__ xhi,
                                                     const float* __restrict__ sq,
                                                     int* __restrict__ cand) {
  __shared__ __align__(16) char lds[2 * LBUF2];   // 17408 B

  const int lane = threadIdx.x & 63;
  const int w = threadIdx.x >> 6;
  const int seg = __builtin_amdgcn_readfirstlane(blockIdx.x & 7);
  const int rowgroup = __builtin_amdgcn_readfirstlane((blockIdx.x >> 3) * 4 + w);
  const int rowbase = rowgroup * 16;
  const int segbase = seg * SEGC;
  const int r0 = lane & 15;
  const int g8 = (lane >> 4) * 8;
  const int cg4 = (lane >> 4) * 4;
  const int selfid = rowbase + r0;

  // staging: each thread stages 2 rows (st_row, st_row+16), one 16B chunk each
  const int st_row = 4 * w + (lane >> 4);          // 0..15
  const int st_chunk = lane & 15;
  const size_t st_src0 = (size_t)st_row * DIM + st_chunk * 8;
  const size_t st_src1 = (size_t)(st_row + 16) * DIM + st_chunk * 8;
  char* const st_dst0 = &lds[st_row * LROW + st_chunk * 16];
  char* const st_dst1 = &lds[(st_row + 16) * LROW + st_chunk * 16];

  // stationary B: this wave's 16 row-features
  f16x8 b[4];
  {
    const size_t rb = (size_t)(rowbase + r0) * DIM + g8;
    #pragma unroll
    for (int ks = 0; ks < 4; ks++) b[ks] = *(const f16x8*)&xhi[rb + ks * 32];
  }

  unsigned pool[KP2];
  #pragma unroll
  for (int j = 0; j < KP2; j++) pool[j] = 0xFFFFFFFFu;

  // prologue: stage tile 0 into buf 0
  {
    const float4 g0 = *(const float4*)&xhi[(size_t)segbase * DIM + st_src0];
    const float4 g1 = *(const float4*)&xhi[(size_t)segbase * DIM + st_src1];
    *(float4*)(st_dst0) = g0;
    *(float4*)(st_dst1) = g1;
  }
  f32x4 sA0 = *(const f32x4*)&sq[segbase + cg4];
  f32x4 sA1 = *(const f32x4*)&sq[segbase + 16 + cg4];
  __syncthreads();

  int cur = 0;
  for (int t = 0; t < TILES32; t++) {
    const int tn = (t + 1) & (TILES32 - 1);
    const size_t nb = (size_t)(segbase + tn * 32) * DIM;
    const float4 g0 = *(const float4*)&xhi[nb + st_src0];
    const float4 g1 = *(const float4*)&xhi[nb + st_src1];
    const f32x4 sN0 = *(const f32x4*)&sq[segbase + tn * 32 + cg4];
    const f32x4 sN1 = *(const f32x4*)&sq[segbase + tn * 32 + 16 + cg4];

    // fragments for both 16-col subtiles
    const char* rb0 = &lds[cur * LBUF2 + r0 * LROW + g8 * 2];
    const char* rb1 = &lds[cur * LBUF2 + (16 + r0) * LROW + g8 * 2];
    f16x8 a0[4], a1[4];
    #pragma unroll
    for (int ks = 0; ks < 4; ks++) {
      a0[ks] = *(const f16x8*)(rb0 + ks * 64);
      a1[ks] = *(const f16x8*)(rb1 + ks * 64);
    }

    f32x4 acc0 = {0.f, 0.f, 0.f, 0.f};
    f32x4 acc1 = {0.f, 0.f, 0.f, 0.f};
    #pragma unroll
    for (int ks = 0; ks < 4; ks++) {
      acc0 = __builtin_amdgcn_mfma_f32_16x16x32_f16(a0[ks], b[ks], acc0, 0, 0, 0);
      acc1 = __builtin_amdgcn_mfma_f32_16x16x32_f16(a1[ks], b[ks], acc1, 0, 0, 0);
    }

    insert4s(acc0, sA0, segbase + t * 32 + cg4, selfid, pool);
    insert4s(acc1, sA1, segbase + t * 32 + 16 + cg4, selfid, pool);

    // write staged tile t+1 into the other buffer, then single barrier
    *(float4*)(st_dst0 + (cur ^ 1) * LBUF2) = g0;
    *(float4*)(st_dst1 + (cur ^ 1) * LBUF2) = g1;
    __syncthreads();
    sA0 = sN0; sA1 = sN1;
    cur ^= 1;
  }

  // dump: row = rowbase + r0; slot block = (lanegroup, seg)
  const int row = rowbase + r0;
  int* dst = cand + (size_t)row * NCAND + ((lane >> 4) * NSEG + seg) * KP2;
  #pragma unroll
  for (int e = 0; e < KP2; e++) dst[e] = (int)(pool[e] & 0x3FFFu);
}

// ---------------- refine v4: coalesced gather (8 lanes per candidate row) ----------------
__device__ __forceinline__ unsigned flip32(float f) {
  unsigned u = __float_as_uint(f);
  return u ^ (unsigned)(((int)u >> 31) | 0x80000000u);
}
__device__ __forceinline__ u64 umin64(u64 a, u64 b) { return a < b ? a : b; }

__global__ __launch_bounds__(256) void refine_kernel(const float* __restrict__ x,
                                                     const float* __restrict__ sq,
                                                     const int* __restrict__ cand,
                                                     int* __restrict__ idxo) {
  __shared__ __align__(16) float Xrow[4][DIM];     // 2 KB
  __shared__ u64 Keys[4][NCAND];                   // 6 KB
  const int wv = threadIdx.x >> 6;
  const int lane = threadIdx.x & 63;
  const int row = blockIdx.x * 4 + wv;

  {
    const float2 v = *(const float2*)&x[(size_t)row * DIM + lane * 2];
    *(float2*)&Xrow[wv][lane * 2] = v;
  }

  const int cs = lane >> 3;    // candidate slot within iteration (0..7)
  const int ch8 = lane & 7;    // 16B chunk id (0..7)
  const int base = row * NCAND;
  const float sr = sq[row];

  #pragma nounroll
  for (int it = 0; it < NCAND / 8; it++) {
    const int ci = it * 8 + cs;
    const int c = cand[base + ci];
    const float4* p = (const float4*)&x[(size_t)c * DIM];
    float d = 0.f;
    #pragma unroll
    for (int j = 0; j < 4; j++) {
      const float4 a = p[ch8 + 8 * j];
      const float4 xv = *(const float4*)&Xrow[wv][(ch8 + 8 * j) * 4];
      d += xv.x * a.x + xv.y * a.y + xv.z * a.z + xv.w * a.w;
    }
    d += __shfl_xor(d, 1);
    d += __shfl_xor(d, 2);
    d += __shfl_xor(d, 4);
    if (ch8 == 0) {
      const float dist = sr + sq[c] - 2.f * d;
      Keys[wv][ci] = ((u64)flip32(dist) << 32) | (unsigned)c;
    }
  }

  u64 k0 = Keys[wv][lane];
  u64 k1 = Keys[wv][64 + lane];
  u64 k2 = Keys[wv][128 + lane];

  int* dst = idxo + (size_t)row * KNN;
  #pragma unroll
  for (int e = 0; e < KNN; e++) {
    u64 m = umin64(k0, umin64(k1, k2));
    #pragma unroll
    for (int off = 32; off > 0; off >>= 1) {
      const u64 o = __shfl_xor(m, off);
      m = umin64(m, o);
    }
    if (k0 == m)      { dst[e] = (int)(unsigned)m; k0 = ~0ull; }
    else if (k1 == m) { dst[e] = (int)(unsigned)m; k1 = ~0ull; }
    else if (k2 == m) { dst[e] = (int)(unsigned)m; k2 = ~0ull; }
  }
}

// ---------------- attention epilogue (4 nodes / 256-thr block, f16x2 channels) ----------------
__global__ __launch_bounds__(256) void attn_kernel(const _Float16* __restrict__ xl,
                                                   const _Float16* __restrict__ xr,
                                                   const float* __restrict__ att,
                                                   const float* __restrict__ bias,
                                                   const int* __restrict__ idxo,
                                                   float* __restrict__ out) {
  const int n = blockIdx.x * 4 + (threadIdx.x >> 6);
  const int lane = threadIdx.x & 63;
  const int ch = lane * 2;
  int myn = 0;
  if (lane < KNN) myn = idxo[(size_t)n * KNN + lane];
  float o0 = 0.f, o1 = 0.f;
  #pragma unroll
  for (int h = 0; h < 3; h++) {
    const f16x2 rr = *(const f16x2*)&xr[(size_t)n * HC + h * 128 + ch];
    const float r0 = (float)rr[0], r1 = (float)rr[1];
    const float2 av = *(const float2*)&att[h * 128 + ch];
    float v0[KNN], v1[KNN], e[KNN];
    #pragma unroll
    for (int kk = 0; kk < KNN; kk++) {
      const f16x2 xv = *(const f16x2*)&xl[(size_t)__shfl(myn, kk) * HC + h * 128 + ch];
      const float x0 = (float)xv[0], x1 = (float)xv[1];
      v0[kk] = x0; v1[kk] = x1;
      float g0 = x0 + r0; g0 = g0 >= 0.f ? g0 : NEG_SLOPE * g0;
      float g1 = x1 + r1; g1 = g1 >= 0.f ? g1 : NEG_SLOPE * g1;
      float p = av.x * g0 + av.y * g1;
      #pragma unroll
      for (int off = 32; off > 0; off >>= 1) p += __shfl_xor(p, off);
      e[kk] = p;
    }
    float m = e[0];
    #pragma unroll
    for (int kk = 1; kk < KNN; kk++) m = fmaxf(m, e[kk]);
    float s = 0.f;
    float w[KNN];
    #pragma unroll
    for (int kk = 0; kk < KNN; kk++) { w[kk] = expf(e[kk] - m); s += w[kk]; }
    #pragma unroll
    for (int kk = 0; kk < KNN; kk++) {
      const float al = w[kk] / s;
      o0 += al * v0[kk];
      o1 += al * v1[kk];
    }
  }
  const float2 bv = *(const float2*)&bias[ch];
  float2 ov;
  ov.x = o0 / 3.f + bv.x;
  ov.y = o1 / 3.f + bv.y;
  *(float2*)&out[(size_t)n * 128 + ch] = ov;
}

extern "C" void kernel_launch(void* const* d_in, const int* in_sizes, int n_in,
                              void* d_out, int out_size, void* d_ws, size_t ws_size,
                              hipStream_t stream) {
  const float* x    = (const float*)d_in[0];
  const float* Wl   = (const float*)d_in[1];
  const float* Wr   = (const float*)d_in[2];
  const float* att  = (const float*)d_in[3];
  const float* bias = (const float*)d_in[4];
  float* out = (float*)d_out;

  _Float16* xhi  = (_Float16*)d_ws;                    // N*128
  _Float16* xlo  = xhi + (size_t)N_NODES * DIM;        // N*128
  _Float16* wthi = xlo + (size_t)N_NODES * DIM;        // 2*384*128
  _Float16* wtlo = wthi + 2 * HC * DIM;
  _Float16* xl   = wtlo + 2 * HC * DIM;                // N*384
  _Float16* xr   = xl + (size_t)N_NODES * HC;          // N*384
  float*    sqv  = (float*)(xr + (size_t)N_NODES * HC);
  int*      cnd  = (int*)(sqv + N_NODES);              // N*192
  int*      idx  = cnd + (size_t)N_NODES * NCAND;      // N*16

  prep_x<<<N_NODES / 4, 256, 0, stream>>>(x, sqv, xhi, xlo);
  prep_w<<<384, 256, 0, stream>>>(Wl, Wr, wthi, wtlo);
  gemm_xw_mfma<<<3072, 256, 0, stream>>>(xhi, xlo, wthi, wtlo, xl, xr);
  knn_kernel<<<(N_NODES / 64) * NSEG, 256, 0, stream>>>(xhi, sqv, cnd);
  refine_kernel<<<N_NODES / 4, 256, 0, stream>>>(x, sqv, cnd, idx);
  attn_kernel<<<N_NODES / 4, 256, 0, stream>>>(xl, xr, att, bias, idx, out);
}

// Round 20
// 381.626 us; speedup vs baseline: 1.1150x; 1.0679x over previous
//
#include <hip/hip_runtime.h>
#include <math.h>

#define N_NODES 16384
#define DIM 128
#define HC 384          // HEADS * C
#define NEG_SLOPE 0.2f
#define KNN 16
#define KP2 6           // per-lane register pool size (per row)
#define NSEG 8
#define NCAND 192       // 4 lane-groups * NSEG * KP2 = 64*3
#define SEGC (N_NODES / NSEG)   // 2048
#define TILES32 (SEGC / 32)     // 64
#define LROW 272        // padded LDS row stride (bytes)
#define LBUF2 (32 * LROW)       // 8704 B per buffer (32 rows)

typedef _Float16 f16x8 __attribute__((ext_vector_type(8)));
typedef _Float16 f16x2 __attribute__((ext_vector_type(2)));
typedef float f32x4 __attribute__((ext_vector_type(4)));
typedef unsigned long long u64;

// ---------------- prep 1: sq + split x into f16 hi/lo ----------------
__global__ __launch_bounds__(256) void prep_x(const float* __restrict__ x,
                                              float* __restrict__ sq,
                                              _Float16* __restrict__ xhi,
                                              _Float16* __restrict__ xlo) {
  const int wv = threadIdx.x >> 6;
  const int lane = threadIdx.x & 63;
  const int row = blockIdx.x * 4 + wv;
  const float2 v = *(const float2*)&x[row * DIM + lane * 2];
  float s = v.x * v.x + v.y * v.y;
  #pragma unroll
  for (int off = 32; off > 0; off >>= 1) s += __shfl_down(s, off);
  _Float16 h0 = (_Float16)v.x, h1 = (_Float16)v.y;
  _Float16 l0 = (_Float16)(v.x - (float)h0), l1 = (_Float16)(v.y - (float)h1);
  f16x2 hh; hh[0] = h0; hh[1] = h1;
  f16x2 ll; ll[0] = l0; ll[1] = l1;
  *(f16x2*)&xhi[row * DIM + lane * 2] = hh;
  *(f16x2*)&xlo[row * DIM + lane * 2] = ll;
  if (lane == 0) sq[row] = s;
}

// ---------------- prep 2: W transpose + split (WT[c][k]) ----------------
__global__ __launch_bounds__(256) void prep_w(const float* __restrict__ Wl,
                                              const float* __restrict__ Wr,
                                              _Float16* __restrict__ wthi,
                                              _Float16* __restrict__ wtlo) {
  const int t = blockIdx.x * 256 + threadIdx.x;   // [0, 98304)
  const int mat = t / 49152;
  const int e = t - mat * 49152;                  // e = k*384 + c
  const int k = e / HC;
  const int c = e - k * HC;
  const float w = (mat ? Wr : Wl)[e];
  _Float16 h = (_Float16)w;
  _Float16 l = (_Float16)(w - (float)h);
  wthi[mat * 49152 + c * DIM + k] = h;
  wtlo[mat * 49152 + c * DIM + k] = l;
}

// ---------------- xl = x@Wl, xr = x@Wr via MFMA f16-split (16x64 per wave) ----------------
__global__ __launch_bounds__(256) void gemm_xw_mfma(const _Float16* __restrict__ xhi,
                                                    const _Float16* __restrict__ xlo,
                                                    const _Float16* __restrict__ wthi,
                                                    const _Float16* __restrict__ wtlo,
                                                    _Float16* __restrict__ xl,
                                                    _Float16* __restrict__ xr) {
  const int lane = threadIdx.x & 63;
  const int wid = blockIdx.x * 4 + (threadIdx.x >> 6);  // [0, 12288)
  const int mat = wid / 6144;
  const int rem = wid - mat * 6144;
  const int rt = rem / 6;          // row tile [0,1024)
  const int ctg = rem - rt * 6;    // col group [0,6): 4 col-tiles each
  const int r0 = lane & 15;
  const int g8 = (lane >> 4) * 8;

  const _Float16* ap_hi = xhi + (size_t)(rt * 16 + r0) * DIM + g8;
  const _Float16* ap_lo = xlo + (size_t)(rt * 16 + r0) * DIM + g8;
  f16x8 ah[4], al[4];
  #pragma unroll
  for (int ks = 0; ks < 4; ks++) {
    ah[ks] = *(const f16x8*)(ap_hi + ks * 32);
    al[ks] = *(const f16x8*)(ap_lo + ks * 32);
  }
  _Float16* o = mat ? xr : xl;

  #pragma unroll
  for (int ct4 = 0; ct4 < 4; ct4++) {
    const int ct = ctg * 4 + ct4;
    const _Float16* bp_hi = wthi + mat * 49152 + (ct * 16 + r0) * DIM + g8;
    const _Float16* bp_lo = wtlo + mat * 49152 + (ct * 16 + r0) * DIM + g8;
    f32x4 acc = {0.f, 0.f, 0.f, 0.f};
    #pragma unroll
    for (int ks = 0; ks < 4; ks++) {
      f16x8 bh = *(const f16x8*)(bp_hi + ks * 32);
      f16x8 bl = *(const f16x8*)(bp_lo + ks * 32);
      acc = __builtin_amdgcn_mfma_f32_16x16x32_f16(ah[ks], bh, acc, 0, 0, 0);
      acc = __builtin_amdgcn_mfma_f32_16x16x32_f16(ah[ks], bl, acc, 0, 0, 0);
      acc = __builtin_amdgcn_mfma_f32_16x16x32_f16(al[ks], bh, acc, 0, 0, 0);
    }
    #pragma unroll
    for (int i = 0; i < 4; i++) {
      const int row = rt * 16 + (lane >> 4) * 4 + i;
      o[(size_t)row * HC + ct * 16 + r0] = (_Float16)acc[i];
    }
  }
}

// ---------------- knn: 32 rows/wave, LDS-shared 32-col tiles, packed-u32 top-6 ----------------
__device__ __forceinline__ unsigned umin32(unsigned a, unsigned b) { return a < b ? a : b; }
__device__ __forceinline__ unsigned umax32(unsigned a, unsigned b) { return a > b ? a : b; }

__device__ __forceinline__ void ripple(unsigned pk, unsigned* pool) {
  unsigned cur = pk;
  #pragma unroll
  for (int s = 0; s < KP2; s++) {
    const unsigned mn = umin32(cur, pool[s]);
    cur = umax32(cur, pool[s]);
    pool[s] = mn;
  }
}

__device__ __forceinline__ void insert4s(const f32x4 acc, const f32x4 scv,
                                         int cb_cg, int selfid, unsigned* pool) {
  unsigned k0, k1, k2, k3;
  {
    unsigned kk[4];
    #pragma unroll
    for (int r = 0; r < 4; r++) {
      const int cid = cb_cg + r;
      const float key = fmaf(-2.f, acc[r], scv[r]);  // d - sr (sr const per lane)
      unsigned u = __float_as_uint(key);
      u ^= (unsigned)(((int)u >> 31) | 0x80000000u); // monotone flip
      unsigned pk = (u & 0xFFFFC000u) | (unsigned)cid;
      kk[r] = (cid == selfid) ? 0xFFFFFFFFu : pk;
    }
    k0 = kk[0]; k1 = kk[1]; k2 = kk[2]; k3 = kk[3];
  }
  #define CSWAP(a, b) { const unsigned mn = umin32(a, b), mx = umax32(a, b); a = mn; b = mx; }
  CSWAP(k0, k1) CSWAP(k2, k3) CSWAP(k0, k2) CSWAP(k1, k3) CSWAP(k1, k2)
  #undef CSWAP
  ripple(k0, pool);
  if (k1 < pool[KP2 - 1]) {
    ripple(k1, pool);
    ripple(k2, pool);
    ripple(k3, pool);
  }
}

// Block = 4 waves x 32 rows = 128 rows, sharing one segment's col tiles via LDS.
// Each a-fragment read feeds TWO MFMAs (row halves) -> LDS traffic per pair halved.
__global__ __launch_bounds__(256, 4) void knn_kernel(const _Float16* __restrict__ xhi,
                                                     const float* __restrict__ sq,
                                                     int* __restrict__ cand) {
  __shared__ __align__(16) char lds[2 * LBUF2];   // 17408 B

  const int lane = threadIdx.x & 63;
  const int w = threadIdx.x >> 6;
  const int seg = __builtin_amdgcn_readfirstlane(blockIdx.x & 7);
  const int blockrow = __builtin_amdgcn_readfirstlane(blockIdx.x >> 3);  // 0..127
  const int rowbase = blockrow * 128 + w * 32;      // wave's 32 rows
  const int segbase = seg * SEGC;
  const int r0 = lane & 15;
  const int g8 = (lane >> 4) * 8;
  const int cg4 = (lane >> 4) * 4;
  const int selfid0 = rowbase + r0;
  const int selfid1 = rowbase + 16 + r0;

  // staging: each thread stages 2 col-rows (st_row, st_row+16), one 16B chunk each
  const int st_row = 4 * w + (lane >> 4);          // 0..15
  const int st_chunk = lane & 15;
  const size_t st_src0 = (size_t)st_row * DIM + st_chunk * 8;
  const size_t st_src1 = (size_t)(st_row + 16) * DIM + st_chunk * 8;
  char* const st_dst0 = &lds[st_row * LROW + st_chunk * 16];
  char* const st_dst1 = &lds[(st_row + 16) * LROW + st_chunk * 16];

  // stationary B: this wave's 32 row-features (two register sets)
  f16x8 b_lo[4], b_hi[4];
  {
    const size_t rb0 = (size_t)(rowbase + r0) * DIM + g8;
    const size_t rb1 = (size_t)(rowbase + 16 + r0) * DIM + g8;
    #pragma unroll
    for (int ks = 0; ks < 4; ks++) {
      b_lo[ks] = *(const f16x8*)&xhi[rb0 + ks * 32];
      b_hi[ks] = *(const f16x8*)&xhi[rb1 + ks * 32];
    }
  }

  unsigned pool0[KP2], pool1[KP2];
  #pragma unroll
  for (int j = 0; j < KP2; j++) { pool0[j] = 0xFFFFFFFFu; pool1[j] = 0xFFFFFFFFu; }

  // prologue: stage tile 0 into buf 0
  {
    const float4 g0 = *(const float4*)&xhi[(size_t)segbase * DIM + st_src0];
    const float4 g1 = *(const float4*)&xhi[(size_t)segbase * DIM + st_src1];
    *(float4*)(st_dst0) = g0;
    *(float4*)(st_dst1) = g1;
  }
  f32x4 sA0 = *(const f32x4*)&sq[segbase + cg4];
  f32x4 sA1 = *(const f32x4*)&sq[segbase + 16 + cg4];
  __syncthreads();

  int cur = 0;
  for (int t = 0; t < TILES32; t++) {
    const int tn = (t + 1) & (TILES32 - 1);
    const size_t nb = (size_t)(segbase + tn * 32) * DIM;
    const float4 g0 = *(const float4*)&xhi[nb + st_src0];
    const float4 g1 = *(const float4*)&xhi[nb + st_src1];
    const f32x4 sN0 = *(const f32x4*)&sq[segbase + tn * 32 + cg4];
    const f32x4 sN1 = *(const f32x4*)&sq[segbase + tn * 32 + 16 + cg4];

    // fragments for both 16-col subtiles
    const char* rb0 = &lds[cur * LBUF2 + r0 * LROW + g8 * 2];
    const char* rb1 = &lds[cur * LBUF2 + (16 + r0) * LROW + g8 * 2];
    f16x8 a0[4], a1[4];
    #pragma unroll
    for (int ks = 0; ks < 4; ks++) {
      a0[ks] = *(const f16x8*)(rb0 + ks * 64);
      a1[ks] = *(const f16x8*)(rb1 + ks * 64);
    }

    // 4 accumulators: (subtile, row-half); each a-read feeds 2 MFMAs
    f32x4 acc00 = {0.f, 0.f, 0.f, 0.f};
    f32x4 acc01 = {0.f, 0.f, 0.f, 0.f};
    f32x4 acc10 = {0.f, 0.f, 0.f, 0.f};
    f32x4 acc11 = {0.f, 0.f, 0.f, 0.f};
    #pragma unroll
    for (int ks = 0; ks < 4; ks++) {
      acc00 = __builtin_amdgcn_mfma_f32_16x16x32_f16(a0[ks], b_lo[ks], acc00, 0, 0, 0);
      acc01 = __builtin_amdgcn_mfma_f32_16x16x32_f16(a0[ks], b_hi[ks], acc01, 0, 0, 0);
      acc10 = __builtin_amdgcn_mfma_f32_16x16x32_f16(a1[ks], b_lo[ks], acc10, 0, 0, 0);
      acc11 = __builtin_amdgcn_mfma_f32_16x16x32_f16(a1[ks], b_hi[ks], acc11, 0, 0, 0);
    }

    const int cb = segbase + t * 32;
    insert4s(acc00, sA0, cb + cg4,      selfid0, pool0);
    insert4s(acc01, sA0, cb + cg4,      selfid1, pool1);
    insert4s(acc10, sA1, cb + 16 + cg4, selfid0, pool0);
    insert4s(acc11, sA1, cb + 16 + cg4, selfid1, pool1);

    // write staged tile t+1 into the other buffer, then single barrier
    *(float4*)(st_dst0 + (cur ^ 1) * LBUF2) = g0;
    *(float4*)(st_dst1 + (cur ^ 1) * LBUF2) = g1;
    __syncthreads();
    sA0 = sN0; sA1 = sN1;
    cur ^= 1;
  }

  // dump: two rows per lane; slot block = (lanegroup, seg)
  const int slot = ((lane >> 4) * NSEG + seg) * KP2;
  int* dst0 = cand + (size_t)(rowbase + r0) * NCAND + slot;
  int* dst1 = cand + (size_t)(rowbase + 16 + r0) * NCAND + slot;
  #pragma unroll
  for (int e = 0; e < KP2; e++) {
    dst0[e] = (int)(pool0[e] & 0x3FFFu);
    dst1[e] = (int)(pool1[e] & 0x3FFFu);
  }
}

// ---------------- refine v4: coalesced gather (8 lanes per candidate row) ----------------
__device__ __forceinline__ unsigned flip32(float f) {
  unsigned u = __float_as_uint(f);
  return u ^ (unsigned)(((int)u >> 31) | 0x80000000u);
}
__device__ __forceinline__ u64 umin64(u64 a, u64 b) { return a < b ? a : b; }

__global__ __launch_bounds__(256) void refine_kernel(const float* __restrict__ x,
                                                     const float* __restrict__ sq,
                                                     const int* __restrict__ cand,
                                                     int* __restrict__ idxo) {
  __shared__ __align__(16) float Xrow[4][DIM];     // 2 KB
  __shared__ u64 Keys[4][NCAND];                   // 6 KB
  const int wv = threadIdx.x >> 6;
  const int lane = threadIdx.x & 63;
  const int row = blockIdx.x * 4 + wv;

  {
    const float2 v = *(const float2*)&x[(size_t)row * DIM + lane * 2];
    *(float2*)&Xrow[wv][lane * 2] = v;
  }

  const int cs = lane >> 3;    // candidate slot within iteration (0..7)
  const int ch8 = lane & 7;    // 16B chunk id (0..7)
  const int base = row * NCAND;
  const float sr = sq[row];

  #pragma nounroll
  for (int it = 0; it < NCAND / 8; it++) {
    const int ci = it * 8 + cs;
    const int c = cand[base + ci];
    const float4* p = (const float4*)&x[(size_t)c * DIM];
    float d = 0.f;
    #pragma unroll
    for (int j = 0; j < 4; j++) {
      const float4 a = p[ch8 + 8 * j];
      const float4 xv = *(const float4*)&Xrow[wv][(ch8 + 8 * j) * 4];
      d += xv.x * a.x + xv.y * a.y + xv.z * a.z + xv.w * a.w;
    }
    d += __shfl_xor(d, 1);
    d += __shfl_xor(d, 2);
    d += __shfl_xor(d, 4);
    if (ch8 == 0) {
      const float dist = sr + sq[c] - 2.f * d;
      Keys[wv][ci] = ((u64)flip32(dist) << 32) | (unsigned)c;
    }
  }

  u64 k0 = Keys[wv][lane];
  u64 k1 = Keys[wv][64 + lane];
  u64 k2 = Keys[wv][128 + lane];

  int* dst = idxo + (size_t)row * KNN;
  #pragma unroll
  for (int e = 0; e < KNN; e++) {
    u64 m = umin64(k0, umin64(k1, k2));
    #pragma unroll
    for (int off = 32; off > 0; off >>= 1) {
      const u64 o = __shfl_xor(m, off);
      m = umin64(m, o);
    }
    if (k0 == m)      { dst[e] = (int)(unsigned)m; k0 = ~0ull; }
    else if (k1 == m) { dst[e] = (int)(unsigned)m; k1 = ~0ull; }
    else if (k2 == m) { dst[e] = (int)(unsigned)m; k2 = ~0ull; }
  }
}

// ---------------- attention epilogue (4 nodes / 256-thr block, f16x2 channels) ----------------
__global__ __launch_bounds__(256) void attn_kernel(const _Float16* __restrict__ xl,
                                                   const _Float16* __restrict__ xr,
                                                   const float* __restrict__ att,
                                                   const float* __restrict__ bias,
                                                   const int* __restrict__ idxo,
                                                   float* __restrict__ out) {
  const int n = blockIdx.x * 4 + (threadIdx.x >> 6);
  const int lane = threadIdx.x & 63;
  const int ch = lane * 2;
  int myn = 0;
  if (lane < KNN) myn = idxo[(size_t)n * KNN + lane];
  float o0 = 0.f, o1 = 0.f;
  #pragma unroll
  for (int h = 0; h < 3; h++) {
    const f16x2 rr = *(const f16x2*)&xr[(size_t)n * HC + h * 128 + ch];
    const float r0 = (float)rr[0], r1 = (float)rr[1];
    const float2 av = *(const float2*)&att[h * 128 + ch];
    float v0[KNN], v1[KNN], e[KNN];
    #pragma unroll
    for (int kk = 0; kk < KNN; kk++) {
      const f16x2 xv = *(const f16x2*)&xl[(size_t)__shfl(myn, kk) * HC + h * 128 + ch];
      const float x0 = (float)xv[0], x1 = (float)xv[1];
      v0[kk] = x0; v1[kk] = x1;
      float g0 = x0 + r0; g0 = g0 >= 0.f ? g0 : NEG_SLOPE * g0;
      float g1 = x1 + r1; g1 = g1 >= 0.f ? g1 : NEG_SLOPE * g1;
      float p = av.x * g0 + av.y * g1;
      #pragma unroll
      for (int off = 32; off > 0; off >>= 1) p += __shfl_xor(p, off);
      e[kk] = p;
    }
    float m = e[0];
    #pragma unroll
    for (int kk = 1; kk < KNN; kk++) m = fmaxf(m, e[kk]);
    float s = 0.f;
    float w[KNN];
    #pragma unroll
    for (int kk = 0; kk < KNN; kk++) { w[kk] = expf(e[kk] - m); s += w[kk]; }
    #pragma unroll
    for (int kk = 0; kk < KNN; kk++) {
      const float al = w[kk] / s;
      o0 += al * v0[kk];
      o1 += al * v1[kk];
    }
  }
  const float2 bv = *(const float2*)&bias[ch];
  float2 ov;
  ov.x = o0 / 3.f + bv.x;
  ov.y = o1 / 3.f + bv.y;
  *(float2*)&out[(size_t)n * 128 + ch] = ov;
}

extern "C" void kernel_launch(void* const* d_in, const int* in_sizes, int n_in,
                              void* d_out, int out_size, void* d_ws, size_t ws_size,
                              hipStream_t stream) {
  const float* x    = (const float*)d_in[0];
  const float* Wl   = (const float*)d_in[1];
  const float* Wr   = (const float*)d_in[2];
  const float* att  = (const float*)d_in[3];
  const float* bias = (const float*)d_in[4];
  float* out = (float*)d_out;

  _Float16* xhi  = (_Float16*)d_ws;                    // N*128
  _Float16* xlo  = xhi + (size_t)N_NODES * DIM;        // N*128
  _Float16* wthi = xlo + (size_t)N_NODES * DIM;        // 2*384*128
  _Float16* wtlo = wthi + 2 * HC * DIM;
  _Float16* xl   = wtlo + 2 * HC * DIM;                // N*384
  _Float16* xr   = xl + (size_t)N_NODES * HC;          // N*384
  float*    sqv  = (float*)(xr + (size_t)N_NODES * HC);
  int*      cnd  = (int*)(sqv + N_NODES);              // N*192
  int*      idx  = cnd + (size_t)N_NODES * NCAND;      // N*16

  prep_x<<<N_NODES / 4, 256, 0, stream>>>(x, sqv, xhi, xlo);
  prep_w<<<384, 256, 0, stream>>>(Wl, Wr, wthi, wtlo);
  gemm_xw_mfma<<<3072, 256, 0, stream>>>(xhi, xlo, wthi, wtlo, xl, xr);
  knn_kernel<<<(N_NODES / 128) * NSEG, 256, 0, stream>>>(xhi, sqv, cnd);
  refine_kernel<<<N_NODES / 4, 256, 0, stream>>>(x, sqv, cnd, idx);
  attn_kernel<<<N_NODES / 4, 256, 0, stream>>>(xl, xr, att, bias, idx, out);
}

// Round 21
// 376.873 us; speedup vs baseline: 1.1291x; 1.0126x over previous
//
#include <hip/hip_runtime.h>
#include <math.h>

#define N_NODES 16384
#define DIM 128
#define HC 384          // HEADS * C
#define NEG_SLOPE 0.2f
#define KNN 16
#define KP2 6           // per-lane register pool size (per row)
#define NSEG 8
#define NCAND 192       // 4 lane-groups * NSEG * KP2 = 64*3
#define SEGC (N_NODES / NSEG)   // 2048
#define TILES64 (SEGC / 64)     // 32
#define LROW 272        // padded LDS row stride (bytes)
#define LBUF64 (64 * LROW)      // 17408 B per buffer (64 rows)

typedef _Float16 f16x8 __attribute__((ext_vector_type(8)));
typedef _Float16 f16x2 __attribute__((ext_vector_type(2)));
typedef float f32x4 __attribute__((ext_vector_type(4)));
typedef unsigned long long u64;

// ---------------- prep 1: sq + split x into f16 hi/lo ----------------
__global__ __launch_bounds__(256) void prep_x(const float* __restrict__ x,
                                              float* __restrict__ sq,
                                              _Float16* __restrict__ xhi,
                                              _Float16* __restrict__ xlo) {
  const int wv = threadIdx.x >> 6;
  const int lane = threadIdx.x & 63;
  const int row = blockIdx.x * 4 + wv;
  const float2 v = *(const float2*)&x[row * DIM + lane * 2];
  float s = v.x * v.x + v.y * v.y;
  #pragma unroll
  for (int off = 32; off > 0; off >>= 1) s += __shfl_down(s, off);
  _Float16 h0 = (_Float16)v.x, h1 = (_Float16)v.y;
  _Float16 l0 = (_Float16)(v.x - (float)h0), l1 = (_Float16)(v.y - (float)h1);
  f16x2 hh; hh[0] = h0; hh[1] = h1;
  f16x2 ll; ll[0] = l0; ll[1] = l1;
  *(f16x2*)&xhi[row * DIM + lane * 2] = hh;
  *(f16x2*)&xlo[row * DIM + lane * 2] = ll;
  if (lane == 0) sq[row] = s;
}

// ---------------- prep 2: W transpose + split (WT[c][k]) ----------------
__global__ __launch_bounds__(256) void prep_w(const float* __restrict__ Wl,
                                              const float* __restrict__ Wr,
                                              _Float16* __restrict__ wthi,
                                              _Float16* __restrict__ wtlo) {
  const int t = blockIdx.x * 256 + threadIdx.x;   // [0, 98304)
  const int mat = t / 49152;
  const int e = t - mat * 49152;                  // e = k*384 + c
  const int k = e / HC;
  const int c = e - k * HC;
  const float w = (mat ? Wr : Wl)[e];
  _Float16 h = (_Float16)w;
  _Float16 l = (_Float16)(w - (float)h);
  wthi[mat * 49152 + c * DIM + k] = h;
  wtlo[mat * 49152 + c * DIM + k] = l;
}

// ---------------- xl = x@Wl, xr = x@Wr via MFMA f16-split (A reused across mats) ----------------
__global__ __launch_bounds__(256) void gemm_xw_mfma(const _Float16* __restrict__ xhi,
                                                    const _Float16* __restrict__ xlo,
                                                    const _Float16* __restrict__ wthi,
                                                    const _Float16* __restrict__ wtlo,
                                                    _Float16* __restrict__ xl,
                                                    _Float16* __restrict__ xr) {
  const int lane = threadIdx.x & 63;
  const int wid = blockIdx.x * 4 + (threadIdx.x >> 6);  // [0, 6144)
  const int rt = wid / 6;          // row tile [0,1024)
  const int ctg = wid - rt * 6;    // col group [0,6): 4 col-tiles each
  const int r0 = lane & 15;
  const int g8 = (lane >> 4) * 8;

  const _Float16* ap_hi = xhi + (size_t)(rt * 16 + r0) * DIM + g8;
  const _Float16* ap_lo = xlo + (size_t)(rt * 16 + r0) * DIM + g8;
  f16x8 ah[4], al[4];
  #pragma unroll
  for (int ks = 0; ks < 4; ks++) {
    ah[ks] = *(const f16x8*)(ap_hi + ks * 32);
    al[ks] = *(const f16x8*)(ap_lo + ks * 32);
  }

  #pragma unroll
  for (int mat = 0; mat < 2; mat++) {
    _Float16* o = mat ? xr : xl;
    #pragma unroll
    for (int ct4 = 0; ct4 < 4; ct4++) {
      const int ct = ctg * 4 + ct4;
      const _Float16* bp_hi = wthi + mat * 49152 + (ct * 16 + r0) * DIM + g8;
      const _Float16* bp_lo = wtlo + mat * 49152 + (ct * 16 + r0) * DIM + g8;
      f32x4 acc = {0.f, 0.f, 0.f, 0.f};
      #pragma unroll
      for (int ks = 0; ks < 4; ks++) {
        f16x8 bh = *(const f16x8*)(bp_hi + ks * 32);
        f16x8 bl = *(const f16x8*)(bp_lo + ks * 32);
        acc = __builtin_amdgcn_mfma_f32_16x16x32_f16(ah[ks], bh, acc, 0, 0, 0);
        acc = __builtin_amdgcn_mfma_f32_16x16x32_f16(ah[ks], bl, acc, 0, 0, 0);
        acc = __builtin_amdgcn_mfma_f32_16x16x32_f16(al[ks], bh, acc, 0, 0, 0);
      }
      #pragma unroll
      for (int i = 0; i < 4; i++) {
        const int row = rt * 16 + (lane >> 4) * 4 + i;
        o[(size_t)row * HC + ct * 16 + r0] = (_Float16)acc[i];
      }
    }
  }
}

// ---------------- knn: 32 rows/wave, 64-col LDS tiles, packed-u32 top-6 ----------------
__device__ __forceinline__ unsigned umin32(unsigned a, unsigned b) { return a < b ? a : b; }
__device__ __forceinline__ unsigned umax32(unsigned a, unsigned b) { return a > b ? a : b; }

__device__ __forceinline__ void ripple(unsigned pk, unsigned* pool) {
  unsigned cur = pk;
  #pragma unroll
  for (int s = 0; s < KP2; s++) {
    const unsigned mn = umin32(cur, pool[s]);
    cur = umax32(cur, pool[s]);
    pool[s] = mn;
  }
}

__device__ __forceinline__ void insert4s(const f32x4 acc, const f32x4 scv,
                                         int cb_cg, int selfid, unsigned* pool) {
  unsigned k0, k1, k2, k3;
  {
    unsigned kk[4];
    #pragma unroll
    for (int r = 0; r < 4; r++) {
      const int cid = cb_cg + r;
      const float key = fmaf(-2.f, acc[r], scv[r]);  // d - sr (sr const per lane)
      unsigned u = __float_as_uint(key);
      u ^= (unsigned)(((int)u >> 31) | 0x80000000u); // monotone flip
      unsigned pk = (u & 0xFFFFC000u) | (unsigned)cid;
      kk[r] = (cid == selfid) ? 0xFFFFFFFFu : pk;
    }
    k0 = kk[0]; k1 = kk[1]; k2 = kk[2]; k3 = kk[3];
  }
  #define CSWAP(a, b) { const unsigned mn = umin32(a, b), mx = umax32(a, b); a = mn; b = mx; }
  CSWAP(k0, k1) CSWAP(k2, k3) CSWAP(k0, k2) CSWAP(k1, k3) CSWAP(k1, k2)
  #undef CSWAP
  ripple(k0, pool);
  if (k1 < pool[KP2 - 1]) {
    ripple(k1, pool);
    ripple(k2, pool);
    ripple(k3, pool);
  }
}

// Block = 4 waves x 32 rows = 128 rows, sharing one segment's 64-col tiles via LDS.
// Each a-fragment read feeds TWO MFMAs (row halves); 4 subtiles per barrier.
__global__ __launch_bounds__(256, 4) void knn_kernel(const _Float16* __restrict__ xhi,
                                                     const float* __restrict__ sq,
                                                     int* __restrict__ cand) {
  __shared__ __align__(16) char lds[2 * LBUF64];   // 34816 B

  const int lane = threadIdx.x & 63;
  const int w = threadIdx.x >> 6;
  const int seg = __builtin_amdgcn_readfirstlane(blockIdx.x & 7);
  const int blockrow = __builtin_amdgcn_readfirstlane(blockIdx.x >> 3);  // 0..127
  const int rowbase = blockrow * 128 + w * 32;      // wave's 32 rows
  const int segbase = seg * SEGC;
  const int r0 = lane & 15;
  const int g8 = (lane >> 4) * 8;
  const int cg4 = (lane >> 4) * 4;
  const int selfid0 = rowbase + r0;
  const int selfid1 = rowbase + 16 + r0;

  // staging: each thread stages 4 col-rows (st_row + 16k), one 16B chunk each
  const int st_row = 4 * w + (lane >> 4);          // 0..15
  const int st_chunk = lane & 15;
  size_t st_src[4];
  char* st_dst[4];
  #pragma unroll
  for (int k = 0; k < 4; k++) {
    st_src[k] = (size_t)(st_row + 16 * k) * DIM + st_chunk * 8;
    st_dst[k] = &lds[(st_row + 16 * k) * LROW + st_chunk * 16];
  }

  // stationary B: this wave's 32 row-features (two register sets)
  f16x8 b_lo[4], b_hi[4];
  {
    const size_t rb0 = (size_t)(rowbase + r0) * DIM + g8;
    const size_t rb1 = (size_t)(rowbase + 16 + r0) * DIM + g8;
    #pragma unroll
    for (int ks = 0; ks < 4; ks++) {
      b_lo[ks] = *(const f16x8*)&xhi[rb0 + ks * 32];
      b_hi[ks] = *(const f16x8*)&xhi[rb1 + ks * 32];
    }
  }

  unsigned pool0[KP2], pool1[KP2];
  #pragma unroll
  for (int j = 0; j < KP2; j++) { pool0[j] = 0xFFFFFFFFu; pool1[j] = 0xFFFFFFFFu; }

  // prologue: stage tile 0 into buf 0; preload sq(tile 0)
  {
    const size_t tb = (size_t)segbase * DIM;
    #pragma unroll
    for (int k = 0; k < 4; k++)
      *(float4*)(st_dst[k]) = *(const float4*)&xhi[tb + st_src[k]];
  }
  f32x4 sA[4];
  #pragma unroll
  for (int s = 0; s < 4; s++) sA[s] = *(const f32x4*)&sq[segbase + 16 * s + cg4];
  __syncthreads();

  int cur = 0;
  for (int t = 0; t < TILES64; t++) {
    const int tn = (t + 1) & (TILES64 - 1);
    const size_t nb = (size_t)(segbase + tn * 64) * DIM;
    float4 g[4];
    #pragma unroll
    for (int k = 0; k < 4; k++) g[k] = *(const float4*)&xhi[nb + st_src[k]];
    f32x4 sN[4];
    #pragma unroll
    for (int s = 0; s < 4; s++) sN[s] = *(const f32x4*)&sq[segbase + tn * 64 + 16 * s + cg4];

    const int cb = segbase + t * 64;
    // 4 subtiles in 2 register-reuse pairs; each a-read feeds 2 MFMAs
    #pragma unroll
    for (int pr = 0; pr < 2; pr++) {
      const int s0 = pr * 2, s1 = pr * 2 + 1;
      const char* rb0 = &lds[cur * LBUF64 + (16 * s0 + r0) * LROW + g8 * 2];
      const char* rb1 = &lds[cur * LBUF64 + (16 * s1 + r0) * LROW + g8 * 2];
      f16x8 a0[4], a1[4];
      #pragma unroll
      for (int ks = 0; ks < 4; ks++) {
        a0[ks] = *(const f16x8*)(rb0 + ks * 64);
        a1[ks] = *(const f16x8*)(rb1 + ks * 64);
      }
      f32x4 acc00 = {0.f, 0.f, 0.f, 0.f};
      f32x4 acc01 = {0.f, 0.f, 0.f, 0.f};
      f32x4 acc10 = {0.f, 0.f, 0.f, 0.f};
      f32x4 acc11 = {0.f, 0.f, 0.f, 0.f};
      #pragma unroll
      for (int ks = 0; ks < 4; ks++) {
        acc00 = __builtin_amdgcn_mfma_f32_16x16x32_f16(a0[ks], b_lo[ks], acc00, 0, 0, 0);
        acc01 = __builtin_amdgcn_mfma_f32_16x16x32_f16(a0[ks], b_hi[ks], acc01, 0, 0, 0);
        acc10 = __builtin_amdgcn_mfma_f32_16x16x32_f16(a1[ks], b_lo[ks], acc10, 0, 0, 0);
        acc11 = __builtin_amdgcn_mfma_f32_16x16x32_f16(a1[ks], b_hi[ks], acc11, 0, 0, 0);
      }
      insert4s(acc00, sA[s0], cb + 16 * s0 + cg4, selfid0, pool0);
      insert4s(acc01, sA[s0], cb + 16 * s0 + cg4, selfid1, pool1);
      insert4s(acc10, sA[s1], cb + 16 * s1 + cg4, selfid0, pool0);
      insert4s(acc11, sA[s1], cb + 16 * s1 + cg4, selfid1, pool1);
    }

    // write staged tile t+1 into the other buffer, then single barrier
    #pragma unroll
    for (int k = 0; k < 4; k++)
      *(float4*)(st_dst[k] + (cur ^ 1) * LBUF64) = g[k];
    __syncthreads();
    #pragma unroll
    for (int s = 0; s < 4; s++) sA[s] = sN[s];
    cur ^= 1;
  }

  // dump: two rows per lane; slot block = (lanegroup, seg)
  const int slot = ((lane >> 4) * NSEG + seg) * KP2;
  int* dst0 = cand + (size_t)(rowbase + r0) * NCAND + slot;
  int* dst1 = cand + (size_t)(rowbase + 16 + r0) * NCAND + slot;
  #pragma unroll
  for (int e = 0; e < KP2; e++) {
    dst0[e] = (int)(pool0[e] & 0x3FFFu);
    dst1[e] = (int)(pool1[e] & 0x3FFFu);
  }
}

// ---------------- refine v4: coalesced gather (8 lanes per candidate row) ----------------
__device__ __forceinline__ unsigned flip32(float f) {
  unsigned u = __float_as_uint(f);
  return u ^ (unsigned)(((int)u >> 31) | 0x80000000u);
}
__device__ __forceinline__ u64 umin64(u64 a, u64 b) { return a < b ? a : b; }

__global__ __launch_bounds__(256) void refine_kernel(const float* __restrict__ x,
                                                     const float* __restrict__ sq,
                                                     const int* __restrict__ cand,
                                                     int* __restrict__ idxo) {
  __shared__ __align__(16) float Xrow[4][DIM];     // 2 KB
  __shared__ u64 Keys[4][NCAND];                   // 6 KB
  const int wv = threadIdx.x >> 6;
  const int lane = threadIdx.x & 63;
  const int row = blockIdx.x * 4 + wv;

  {
    const float2 v = *(const float2*)&x[(size_t)row * DIM + lane * 2];
    *(float2*)&Xrow[wv][lane * 2] = v;
  }

  const int cs = lane >> 3;    // candidate slot within iteration (0..7)
  const int ch8 = lane & 7;    // 16B chunk id (0..7)
  const int base = row * NCAND;
  const float sr = sq[row];

  #pragma nounroll
  for (int it = 0; it < NCAND / 8; it++) {
    const int ci = it * 8 + cs;
    const int c = cand[base + ci];
    const float4* p = (const float4*)&x[(size_t)c * DIM];
    float d = 0.f;
    #pragma unroll
    for (int j = 0; j < 4; j++) {
      const float4 a = p[ch8 + 8 * j];
      const float4 xv = *(const float4*)&Xrow[wv][(ch8 + 8 * j) * 4];
      d += xv.x * a.x + xv.y * a.y + xv.z * a.z + xv.w * a.w;
    }
    d += __shfl_xor(d, 1);
    d += __shfl_xor(d, 2);
    d += __shfl_xor(d, 4);
    if (ch8 == 0) {
      const float dist = sr + sq[c] - 2.f * d;
      Keys[wv][ci] = ((u64)flip32(dist) << 32) | (unsigned)c;
    }
  }

  u64 k0 = Keys[wv][lane];
  u64 k1 = Keys[wv][64 + lane];
  u64 k2 = Keys[wv][128 + lane];

  int* dst = idxo + (size_t)row * KNN;
  #pragma unroll
  for (int e = 0; e < KNN; e++) {
    u64 m = umin64(k0, umin64(k1, k2));
    #pragma unroll
    for (int off = 32; off > 0; off >>= 1) {
      const u64 o = __shfl_xor(m, off);
      m = umin64(m, o);
    }
    if (k0 == m)      { dst[e] = (int)(unsigned)m; k0 = ~0ull; }
    else if (k1 == m) { dst[e] = (int)(unsigned)m; k1 = ~0ull; }
    else if (k2 == m) { dst[e] = (int)(unsigned)m; k2 = ~0ull; }
  }
}

// ---------------- attention epilogue (4 nodes / 256-thr block, f16x2 channels) ----------------
__global__ __launch_bounds__(256) void attn_kernel(const _Float16* __restrict__ xl,
                                                   const _Float16* __restrict__ xr,
                                                   const float* __restrict__ att,
                                                   const float* __restrict__ bias,
                                                   const int* __restrict__ idxo,
                                                   float* __restrict__ out) {
  const int n = blockIdx.x * 4 + (threadIdx.x >> 6);
  const int lane = threadIdx.x & 63;
  const int ch = lane * 2;
  int myn = 0;
  if (lane < KNN) myn = idxo[(size_t)n * KNN + lane];
  float o0 = 0.f, o1 = 0.f;
  #pragma unroll
  for (int h = 0; h < 3; h++) {
    const f16x2 rr = *(const f16x2*)&xr[(size_t)n * HC + h * 128 + ch];
    const float r0 = (float)rr[0], r1 = (float)rr[1];
    const float2 av = *(const float2*)&att[h * 128 + ch];
    float v0[KNN], v1[KNN], e[KNN];
    #pragma unroll
    for (int kk = 0; kk < KNN; kk++) {
      const f16x2 xv = *(const f16x2*)&xl[(size_t)__shfl(myn, kk) * HC + h * 128 + ch];
      const float x0 = (float)xv[0], x1 = (float)xv[1];
      v0[kk] = x0; v1[kk] = x1;
      float g0 = x0 + r0; g0 = g0 >= 0.f ? g0 : NEG_SLOPE * g0;
      float g1 = x1 + r1; g1 = g1 >= 0.f ? g1 : NEG_SLOPE * g1;
      float p = av.x * g0 + av.y * g1;
      #pragma unroll
      for (int off = 32; off > 0; off >>= 1) p += __shfl_xor(p, off);
      e[kk] = p;
    }
    float m = e[0];
    #pragma unroll
    for (int kk = 1; kk < KNN; kk++) m = fmaxf(m, e[kk]);
    float s = 0.f;
    float w[KNN];
    #pragma unroll
    for (int kk = 0; kk < KNN; kk++) { w[kk] = expf(e[kk] - m); s += w[kk]; }
    #pragma unroll
    for (int kk = 0; kk < KNN; kk++) {
      const float al = w[kk] / s;
      o0 += al * v0[kk];
      o1 += al * v1[kk];
    }
  }
  const float2 bv = *(const float2*)&bias[ch];
  float2 ov;
  ov.x = o0 / 3.f + bv.x;
  ov.y = o1 / 3.f + bv.y;
  *(float2*)&out[(size_t)n * 128 + ch] = ov;
}

extern "C" void kernel_launch(void* const* d_in, const int* in_sizes, int n_in,
                              void* d_out, int out_size, void* d_ws, size_t ws_size,
                              hipStream_t stream) {
  const float* x    = (const float*)d_in[0];
  const float* Wl   = (const float*)d_in[1];
  const float* Wr   = (const float*)d_in[2];
  const float* att  = (const float*)d_in[3];
  const float* bias = (const float*)d_in[4];
  float* out = (float*)d_out;

  _Float16* xhi  = (_Float16*)d_ws;                    // N*128
  _Float16* xlo  = xhi + (size_t)N_NODES * DIM;        // N*128
  _Float16* wthi = xlo + (size_t)N_NODES * DIM;        // 2*384*128
  _Float16* wtlo = wthi + 2 * HC * DIM;
  _Float16* xl   = wtlo + 2 * HC * DIM;                // N*384
  _Float16* xr   = xl + (size_t)N_NODES * HC;          // N*384
  float*    sqv  = (float*)(xr + (size_t)N_NODES * HC);
  int*      cnd  = (int*)(sqv + N_NODES);              // N*192
  int*      idx  = cnd + (size_t)N_NODES * NCAND;      // N*16

  prep_x<<<N_NODES / 4, 256, 0, stream>>>(x, sqv, xhi, xlo);
  prep_w<<<384, 256, 0, stream>>>(Wl, Wr, wthi, wtlo);
  gemm_xw_mfma<<<1536, 256, 0, stream>>>(xhi, xlo, wthi, wtlo, xl, xr);
  knn_kernel<<<(N_NODES / 128) * NSEG, 256, 0, stream>>>(xhi, sqv, cnd);
  refine_kernel<<<N_NODES / 4, 256, 0, stream>>>(x, sqv, cnd, idx);
  attn_kernel<<<N_NODES / 4, 256, 0, stream>>>(xl, xr, att, bias, idx, out);
}